// Round 1
// baseline (1134.143 us; speedup 1.0000x reference)
//
#include <hip/hip_runtime.h>

constexpr int T = 36, P = 64, H = 128, W = 256;
constexpr int HW  = H * W;        // 32768
constexpr int PHW = P * HW;       // 2097152

constexpr int TILE_H = 32, TILE_W = 64;
constexpr int EXT_H = TILE_H + 8, EXT_W = TILE_W + 8;   // 40 x 72 (4-px halo)
constexpr int RH_H  = TILE_H + 4, RH_W  = TILE_W + 4;   // 36 x 68 (2-px halo)

__device__ __forceinline__ float fast_sigmoid(float z) {
    float e = __expf(-z);
    return __builtin_amdgcn_rcpf(1.0f + e);
}
__device__ __forceinline__ float fast_tanh(float x) {
    float e = __expf(-2.0f * fabsf(x));
    float t = (1.0f - e) * __builtin_amdgcn_rcpf(1.0f + e);
    return copysignf(t, x);
}

__global__ __launch_bounds__(256) void gru_step(
    const float* __restrict__ x_t,      // inputs + t*PHW, (P,H,W)
    const float* __restrict__ gam,
    const float* __restrict__ h_prev,
    float* __restrict__ h_next,
    const float* __restrict__ w_update, const float* __restrict__ b_update,
    const float* __restrict__ w_reset,  const float* __restrict__ b_reset,
    const float* __restrict__ w_out,
    const float* __restrict__ add_w,
    float* __restrict__ xs_t)           // xs_base + t*PHW, (P,H,W)
{
    __shared__ float sx[EXT_H][EXT_W];
    __shared__ float sh[EXT_H][EXT_W];
    __shared__ float srh[RH_H][RH_W];

    const int tid = threadIdx.x;
    const int p   = blockIdx.z;
    const int by  = blockIdx.y * TILE_H;
    const int bx  = blockIdx.x * TILE_W;

    const float gamma = gam[p];
    const float* __restrict__ xin = x_t    + (size_t)p * HW;
    const float* __restrict__ hin = h_prev + (size_t)p * HW;

    // ---- stage x (pre-scaled) and h with 4-px halo; OOB = 0 (SAME padding) ----
    for (int i = tid; i < EXT_H * EXT_W; i += 256) {
        const int r  = i / EXT_W;
        const int c  = i - r * EXT_W;
        const int gy = by + r - 4;
        const int gx = bx + c - 4;
        float xv = 0.f, hv = 0.f;
        if (gy >= 0 && gy < H && gx >= 0 && gx < W) {
            const int idx = gy * W + gx;
            xv = gamma * xin[idx];
            hv = hin[idx];
        }
        sx[r][c] = xv;
        sh[r][c] = hv;
    }
    __syncthreads();

    // ---- reset gate + r*h over extended (+2 halo) region: 36 x 68 ----
    {
        const float br = b_reset[0];
        const int cx = tid & 63;          // cols 0..63
        const int r0 = (tid >> 6) * 9;    // 4 row-groups of 9 consecutive rows
        #pragma unroll 3
        for (int k = 0; k < 9; ++k) {
            const int ry = r0 + k;
            float acc = br;
            #pragma unroll
            for (int dy = 0; dy < 5; ++dy)
                #pragma unroll
                for (int dx = 0; dx < 5; ++dx) {
                    acc = fmaf(sx[ry + dy][cx + dx], w_reset[dy * 5 + dx], acc);
                    acc = fmaf(sh[ry + dy][cx + dx], w_reset[25 + dy * 5 + dx], acc);
                }
            srh[ry][cx] = fast_sigmoid(acc) * sh[ry + 2][cx + 2];
        }
        // leftover cols 64..67 (36 rows x 4 cols = 144 positions)
        if (tid < 144) {
            const int ry  = tid >> 2;
            const int cx2 = 64 + (tid & 3);
            float acc = br;
            #pragma unroll
            for (int dy = 0; dy < 5; ++dy)
                #pragma unroll
                for (int dx = 0; dx < 5; ++dx) {
                    acc = fmaf(sx[ry + dy][cx2 + dx], w_reset[dy * 5 + dx], acc);
                    acc = fmaf(sh[ry + dy][cx2 + dx], w_reset[25 + dy * 5 + dx], acc);
                }
            srh[ry][cx2] = fast_sigmoid(acc) * sh[ry + 2][cx2 + 2];
        }
    }
    __syncthreads();

    // ---- interior: u, c, h_new, xs ----
    const float bu  = b_update[0];
    const int ox  = tid & 63;
    const int oy0 = (tid >> 6) * 8;       // 8 consecutive rows per thread
    const float* __restrict__ aw   = add_w  + (size_t)p * HW;
    float* __restrict__ hout = h_next + (size_t)p * HW;
    float* __restrict__ xso  = xs_t   + (size_t)p * HW;

    #pragma unroll 4
    for (int k = 0; k < 8; ++k) {
        const int oy = oy0 + k;
        float uacc = bu;
        float cacc = 0.f;
        #pragma unroll
        for (int dy = 0; dy < 5; ++dy)
            #pragma unroll
            for (int dx = 0; dx < 5; ++dx) {
                const float xv = sx[oy + 2 + dy][ox + 2 + dx];
                const float hv = sh[oy + 2 + dy][ox + 2 + dx];
                uacc = fmaf(xv, w_update[dy * 5 + dx], uacc);
                uacc = fmaf(hv, w_update[25 + dy * 5 + dx], uacc);
                cacc = fmaf(xv, w_out[dy * 5 + dx], cacc);
                cacc = fmaf(srh[oy + dy][ox + dx], w_out[25 + dy * 5 + dx], cacc);
            }
        const float u     = fast_sigmoid(uacc);
        const float h_old = sh[oy + 4][ox + 4];
        const float h_new = h_old + (cacc - h_old) * u;
        const int gidx = (by + oy) * W + (bx + ox);
        hout[gidx] = h_new;
        xso[gidx]  = fast_tanh(h_new) * aw[gidx];
    }
}

// out_y[t,y,x] = bias[y,x] + sum_p xs[t,p,y,x]
__global__ __launch_bounds__(256) void reduce_out(
    const float* __restrict__ xs, const float* __restrict__ bias,
    float* __restrict__ out_y)
{
    const int i = blockIdx.x * 256 + threadIdx.x;
    if (i >= T * HW) return;
    const int t  = i / HW;
    const int yx = i - t * HW;
    const float* __restrict__ src = xs + (size_t)t * PHW + yx;
    float acc = bias[yx];
    #pragma unroll
    for (int p = 0; p < P; ++p) acc += src[(size_t)p * HW];
    out_y[i] = acc;
}

extern "C" void kernel_launch(void* const* d_in, const int* in_sizes, int n_in,
                              void* d_out, int out_size, void* d_ws, size_t ws_size,
                              hipStream_t stream) {
    const float* inputs   = (const float*)d_in[0];
    const float* w_reset  = (const float*)d_in[1];
    const float* b_reset  = (const float*)d_in[2];
    const float* w_update = (const float*)d_in[3];
    const float* b_update = (const float*)d_in[4];
    const float* w_out    = (const float*)d_in[5];
    const float* gam      = (const float*)d_in[6];
    const float* add_w    = (const float*)d_in[7];
    const float* bias     = (const float*)d_in[8];

    float* out_y = (float*)d_out;                 // T*H*W
    float* xs    = out_y + (size_t)T * HW;        // T*P*H*W

    float* h0 = (float*)d_ws;
    float* h1 = h0 + (size_t)PHW;

    hipMemsetAsync(h0, 0, (size_t)PHW * sizeof(float), stream);

    dim3 grid(W / TILE_W, H / TILE_H, P);         // (4, 4, 64) = 1024 blocks
    for (int t = 0; t < T; ++t) {
        const float* hp = (t & 1) ? h1 : h0;
        float*       hn = (t & 1) ? h0 : h1;
        gru_step<<<grid, 256, 0, stream>>>(
            inputs + (size_t)t * PHW, gam, hp, hn,
            w_update, b_update, w_reset, b_reset, w_out,
            add_w, xs + (size_t)t * PHW);
    }

    const int nout = T * HW;
    reduce_out<<<(nout + 255) / 256, 256, 0, stream>>>(xs, bias, out_y);
}

// Round 2
// 1101.023 us; speedup vs baseline: 1.0301x; 1.0301x over previous
//
#include <hip/hip_runtime.h>

constexpr int T = 36, P = 64, H = 128, W = 256;
constexpr int HW  = H * W;        // 32768
constexpr int PHW = P * HW;       // 2097152

constexpr int TILE_H = 32, TILE_W = 64;
constexpr int EXT_H = 40, EXT_W = 72;   // spatial extent with 4-px halo
constexpr int SW    = 76;               // sx/sh storage width (+2 shift, 16B-mult stride)
constexpr int SHIFT = 2;                // storage col = spatial halo col + SHIFT
constexpr int RH_H  = 36, RH_W = 68;    // r*h extent (2-px halo)
constexpr int SRW   = 72;               // srh storage width (16B-mult stride)

__device__ __forceinline__ float fast_sigmoid(float z) {
    float e = __expf(-z);
    return __builtin_amdgcn_rcpf(1.0f + e);
}
__device__ __forceinline__ float fast_tanh(float x) {
    float e = __expf(-2.0f * fabsf(x));
    float t = (1.0f - e) * __builtin_amdgcn_rcpf(1.0f + e);
    return copysignf(t, x);
}

__global__ __launch_bounds__(256) void gru_step(
    const float* __restrict__ x_t,
    const float* __restrict__ gam,
    const float* __restrict__ h_prev,
    float* __restrict__ h_next,
    const float* __restrict__ w_update, const float* __restrict__ b_update,
    const float* __restrict__ w_reset,  const float* __restrict__ b_reset,
    const float* __restrict__ w_out,
    const float* __restrict__ add_w,
    float* __restrict__ xs_t)
{
    __shared__ __align__(16) float sx[EXT_H][SW];
    __shared__ __align__(16) float sh[EXT_H][SW];
    __shared__ __align__(16) float srh[RH_H][SRW];

    const int tid = threadIdx.x;
    const int p   = blockIdx.z;
    const int by  = blockIdx.y * TILE_H;
    const int bx  = blockIdx.x * TILE_W;

    const float gamma = gam[p];
    const float* __restrict__ xin = x_t    + (size_t)p * HW;
    const float* __restrict__ hin = h_prev + (size_t)p * HW;

    // ---- stage x (pre-scaled by gam) and h; OOB = 0 (SAME padding) ----
    for (int i = tid; i < EXT_H * EXT_W; i += 256) {
        const int r  = i / EXT_W;
        const int c  = i - r * EXT_W;
        const int gy = by + r - 4;
        const int gx = bx + c - 4;
        float xv = 0.f, hv = 0.f;
        if ((unsigned)gy < (unsigned)H && (unsigned)gx < (unsigned)W) {
            const int idx = gy * W + gx;
            xv = gamma * xin[idx];
            hv = hin[idx];
        }
        sx[r][c + SHIFT] = xv;
        sh[r][c + SHIFT] = hv;
    }
    __syncthreads();

    // ---- reset gate + r*h over 36 x 68 (+2 halo), sliding-row window ----
    {
        const float br = b_reset[0];
        for (int s = tid; s < 4 * RH_W; s += 256) {       // 272 slots / 256 thr
            const int band = s / RH_W;                     // 0..3
            const int col  = s - band * RH_W;              // 0..67
            const int rb   = band * 9;
            float racc[9];
            #pragma unroll
            for (int k = 0; k < 9; ++k) racc[k] = br;
            #pragma unroll
            for (int ir = 0; ir < 13; ++ir) {
                const int sr = rb + ir;
                float vx[5], vh[5];
                #pragma unroll
                for (int j = 0; j < 5; ++j) {
                    vx[j] = sx[sr][col + SHIFT + j];
                    vh[j] = sh[sr][col + SHIFT + j];
                }
                #pragma unroll
                for (int k = 0; k < 9; ++k) {
                    const int dy = ir - k;
                    if (dy >= 0 && dy <= 4) {
                        #pragma unroll
                        for (int dx = 0; dx < 5; ++dx) {
                            racc[k] = fmaf(vx[dx], w_reset[dy * 5 + dx], racc[k]);
                            racc[k] = fmaf(vh[dx], w_reset[25 + dy * 5 + dx], racc[k]);
                        }
                    }
                }
            }
            #pragma unroll
            for (int k = 0; k < 9; ++k)
                srh[rb + k][col] = fast_sigmoid(racc[k]) * sh[rb + k + 2][col + 2 + SHIFT];
        }
    }
    __syncthreads();

    // ---- interior: u, c convs with 2-row x 4-col register blocking ----
    {
        const float bu = b_update[0];
        const int ox  = (tid & 15) * 4;       // output col 0..60 step 4
        const int oy0 = (tid >> 4) * 2;       // output row 0..30 step 2

        float uacc[2][4], cacc[2][4], hold[2][4];
        #pragma unroll
        for (int k = 0; k < 2; ++k)
            #pragma unroll
            for (int c = 0; c < 4; ++c) { uacc[k][c] = bu; cacc[k][c] = 0.f; }

        #pragma unroll
        for (int ir = 0; ir < 6; ++ir) {
            const int sr = oy0 + 2 + ir;      // sx/sh row
            const float4 xa = *(const float4*)&sx[sr][ox + 4];
            const float4 xb = *(const float4*)&sx[sr][ox + 8];
            const float4 ha = *(const float4*)&sh[sr][ox + 4];
            const float4 hb = *(const float4*)&sh[sr][ox + 8];
            const float4 ra = *(const float4*)&srh[oy0 + ir][ox];
            const float4 rb4 = *(const float4*)&srh[oy0 + ir][ox + 4];
            const float vx[8] = {xa.x, xa.y, xa.z, xa.w, xb.x, xb.y, xb.z, xb.w};
            const float vh[8] = {ha.x, ha.y, ha.z, ha.w, hb.x, hb.y, hb.z, hb.w};
            const float vr[8] = {ra.x, ra.y, ra.z, ra.w, rb4.x, rb4.y, rb4.z, rb4.w};

            if (ir == 2) {        // h_old row oy0   (spatial row oy0+4)
                #pragma unroll
                for (int c = 0; c < 4; ++c) hold[0][c] = vh[c + 2];
            }
            if (ir == 3) {        // h_old row oy0+1
                #pragma unroll
                for (int c = 0; c < 4; ++c) hold[1][c] = vh[c + 2];
            }

            #pragma unroll
            for (int k = 0; k < 2; ++k) {
                const int dy = ir - k;
                if (dy >= 0 && dy <= 4) {
                    #pragma unroll
                    for (int dx = 0; dx < 5; ++dx) {
                        const float wux = w_update[dy * 5 + dx];
                        const float wuh = w_update[25 + dy * 5 + dx];
                        const float wox = w_out[dy * 5 + dx];
                        const float wor = w_out[25 + dy * 5 + dx];
                        #pragma unroll
                        for (int c = 0; c < 4; ++c) {
                            uacc[k][c] = fmaf(vx[c + dx], wux, uacc[k][c]);
                            uacc[k][c] = fmaf(vh[c + dx], wuh, uacc[k][c]);
                            cacc[k][c] = fmaf(vx[c + dx], wox, cacc[k][c]);
                            cacc[k][c] = fmaf(vr[c + dx], wor, cacc[k][c]);
                        }
                    }
                }
            }
        }

        // ---- epilogue: h_new, xs (float4 stores) ----
        const float* __restrict__ aw   = add_w  + (size_t)p * HW;
        float* __restrict__ hout = h_next + (size_t)p * HW;
        float* __restrict__ xso  = xs_t   + (size_t)p * HW;
        #pragma unroll
        for (int k = 0; k < 2; ++k) {
            const int gidx = (by + oy0 + k) * W + (bx + ox);
            const float4 aw4 = *(const float4*)&aw[gidx];
            const float awv[4] = {aw4.x, aw4.y, aw4.z, aw4.w};
            float hn[4], xv[4];
            #pragma unroll
            for (int c = 0; c < 4; ++c) {
                const float u = fast_sigmoid(uacc[k][c]);
                hn[c] = hold[k][c] + (cacc[k][c] - hold[k][c]) * u;
                xv[c] = fast_tanh(hn[c]) * awv[c];
            }
            *(float4*)&hout[gidx] = make_float4(hn[0], hn[1], hn[2], hn[3]);
            *(float4*)&xso[gidx]  = make_float4(xv[0], xv[1], xv[2], xv[3]);
        }
    }
}

// out_y[t,y,x] = bias[y,x] + sum_p xs[t,p,y,x], float4 per thread
__global__ __launch_bounds__(256) void reduce_out(
    const float* __restrict__ xs, const float* __restrict__ bias,
    float* __restrict__ out_y)
{
    const int i4  = blockIdx.x * 256 + threadIdx.x;      // < T*HW/4 = 294912
    const int t   = i4 / (HW / 4);
    const int yx4 = i4 - t * (HW / 4);
    const float4* __restrict__ src = (const float4*)(xs + (size_t)t * PHW) + yx4;
    const float4  b4 = ((const float4*)bias)[yx4];
    float a0[4] = {b4.x, b4.y, b4.z, b4.w};
    float a1[4] = {0.f, 0.f, 0.f, 0.f};
    #pragma unroll 8
    for (int p = 0; p < P; p += 2) {
        const float4 v0 = src[(size_t)p * (HW / 4)];
        const float4 v1 = src[(size_t)(p + 1) * (HW / 4)];
        a0[0] += v0.x; a0[1] += v0.y; a0[2] += v0.z; a0[3] += v0.w;
        a1[0] += v1.x; a1[1] += v1.y; a1[2] += v1.z; a1[3] += v1.w;
    }
    ((float4*)out_y)[i4] = make_float4(a0[0] + a1[0], a0[1] + a1[1],
                                       a0[2] + a1[2], a0[3] + a1[3]);
}

extern "C" void kernel_launch(void* const* d_in, const int* in_sizes, int n_in,
                              void* d_out, int out_size, void* d_ws, size_t ws_size,
                              hipStream_t stream) {
    const float* inputs   = (const float*)d_in[0];
    const float* w_reset  = (const float*)d_in[1];
    const float* b_reset  = (const float*)d_in[2];
    const float* w_update = (const float*)d_in[3];
    const float* b_update = (const float*)d_in[4];
    const float* w_out    = (const float*)d_in[5];
    const float* gam      = (const float*)d_in[6];
    const float* add_w    = (const float*)d_in[7];
    const float* bias     = (const float*)d_in[8];

    float* out_y = (float*)d_out;                 // T*H*W
    float* xs    = out_y + (size_t)T * HW;        // T*P*H*W

    float* h0 = (float*)d_ws;
    float* h1 = h0 + (size_t)PHW;

    hipMemsetAsync(h0, 0, (size_t)PHW * sizeof(float), stream);

    dim3 grid(W / TILE_W, H / TILE_H, P);         // (4, 4, 64) = 1024 blocks
    for (int t = 0; t < T; ++t) {
        const float* hp = (t & 1) ? h1 : h0;
        float*       hn = (t & 1) ? h0 : h1;
        gru_step<<<grid, 256, 0, stream>>>(
            inputs + (size_t)t * PHW, gam, hp, hn,
            w_update, b_update, w_reset, b_reset, w_out,
            add_w, xs + (size_t)t * PHW);
    }

    const int nout4 = T * HW / 4;                 // 294912
    reduce_out<<<nout4 / 256, 256, 0, stream>>>(xs, bias, out_y);
}

// Round 3
// 885.472 us; speedup vs baseline: 1.2808x; 1.2434x over previous
//
#include <hip/hip_runtime.h>

constexpr int T = 36, P = 64, H = 128, W = 256;
constexpr int HW  = H * W;        // 32768
constexpr int PHW = P * HW;       // 2097152

constexpr int TILE_H = 32, TILE_W = 64;
// sx/sh: storage row = spatial + 4 (spatial -4..35), storage col = spatial + 6
// (spatial -6..69; cols 0,1,74,75 are zeroed pads). Width 76 keeps 16B rows.
constexpr int SXH = 40, SW = 76;
// srh: storage row = spatial + 2 (spatial -2..33), storage col = spatial + 6.
constexpr int SRH = 36, SRW = 76;

__device__ __forceinline__ float fast_sigmoid(float z) {
    float e = __expf(-z);
    return __builtin_amdgcn_rcpf(1.0f + e);
}
__device__ __forceinline__ float fast_tanh(float x) {
    float e = __expf(-2.0f * fabsf(x));
    float t = (1.0f - e) * __builtin_amdgcn_rcpf(1.0f + e);
    return copysignf(t, x);
}

__global__ __launch_bounds__(256, 4) void gru_step(
    const float* __restrict__ x_t,
    const float* __restrict__ gam,
    const float* __restrict__ h_prev,
    float* __restrict__ h_next,
    const float* __restrict__ w_update, const float* __restrict__ b_update,
    const float* __restrict__ w_reset,  const float* __restrict__ b_reset,
    const float* __restrict__ w_out,
    const float* __restrict__ add_w,
    float* __restrict__ xs_t)
{
    __shared__ __align__(16) float sx[SXH][SW];
    __shared__ __align__(16) float sh[SXH][SW];
    __shared__ __align__(16) float srh[SRH][SRW];

    const int tid = threadIdx.x;
    const int p   = blockIdx.z;
    const int by  = blockIdx.y * TILE_H;
    const int bx  = blockIdx.x * TILE_W;

    const float gamma = gam[p];
    const float* __restrict__ xin = x_t    + (size_t)p * HW;
    const float* __restrict__ hin = h_prev + (size_t)p * HW;

    // ---- stage: float4 loads, spatial cols -4..67 (18 float4/row), rows -4..35 ----
    for (int i = tid; i < SXH * 18; i += 256) {
        const int r  = i / 18;              // storage row
        const int c4 = i - r * 18;          // float4 index
        const int gy = by + r - 4;
        const int gx = bx + 4 * c4 - 4;     // multiple of 4; all-in or all-out
        float4 xv = make_float4(0.f, 0.f, 0.f, 0.f);
        float4 hv = xv;
        if ((unsigned)gy < (unsigned)H && (unsigned)gx < (unsigned)W) {
            const int idx = gy * W + gx;
            xv = *(const float4*)&xin[idx];
            hv = *(const float4*)&hin[idx];
            xv.x *= gamma; xv.y *= gamma; xv.z *= gamma; xv.w *= gamma;
        }
        const int sc = 2 + 4 * c4;          // storage col (== spatial+6)
        sx[r][sc] = xv.x; sx[r][sc+1] = xv.y; sx[r][sc+2] = xv.z; sx[r][sc+3] = xv.w;
        sh[r][sc] = hv.x; sh[r][sc+1] = hv.y; sh[r][sc+2] = hv.z; sh[r][sc+3] = hv.w;
    }
    // zero pad columns {0,1,74,75}
    if (tid < 160) {
        const int r = tid >> 2;
        const int c = tid & 3;
        const int col = (c < 2) ? c : 72 + c;   // 0,1,74,75
        sx[r][col] = 0.f;
        sh[r][col] = 0.f;
    }
    __syncthreads();

    // ---- reset: 4x4 blocking over spatial rows -2..33, cols -4..67 (9 x 18 slots) ----
    if (tid < 162) {
        const int b = tid / 18;             // row band 0..8  -> spatial rows 4b-2..4b+1
        const int g = tid - b * 18;         // col group 0..17 -> spatial cols 4g-4..4g-1
        const int sr0 = 4 * b;              // window storage rows sr0..sr0+7
        const int scw = 4 * g;              // window storage cols scw..scw+7 (aligned)
        const float br = b_reset[0];
        float racc[4][4], hold[4][4];
        #pragma unroll
        for (int k = 0; k < 4; ++k)
            #pragma unroll
            for (int c = 0; c < 4; ++c) racc[k][c] = br;

        #pragma unroll
        for (int ir = 0; ir < 8; ++ir) {
            const float4 xa = *(const float4*)&sx[sr0 + ir][scw];
            const float4 xb = *(const float4*)&sx[sr0 + ir][scw + 4];
            const float4 ha = *(const float4*)&sh[sr0 + ir][scw];
            const float4 hb = *(const float4*)&sh[sr0 + ir][scw + 4];
            const float vx[8] = {xa.x, xa.y, xa.z, xa.w, xb.x, xb.y, xb.z, xb.w};
            const float vh[8] = {ha.x, ha.y, ha.z, ha.w, hb.x, hb.y, hb.z, hb.w};
            if (ir >= 2 && ir <= 5) {
                #pragma unroll
                for (int c = 0; c < 4; ++c) hold[ir - 2][c] = vh[c + 2];
            }
            #pragma unroll
            for (int k = 0; k < 4; ++k) {
                const int dy = ir - k;
                if (dy >= 0 && dy <= 4) {
                    #pragma unroll
                    for (int dx = 0; dx < 5; ++dx) {
                        const float wx = w_reset[dy * 5 + dx];
                        const float wh = w_reset[25 + dy * 5 + dx];
                        #pragma unroll
                        for (int c = 0; c < 4; ++c) {
                            racc[k][c] = fmaf(vx[c + dx], wx, racc[k][c]);
                            racc[k][c] = fmaf(vh[c + dx], wh, racc[k][c]);
                        }
                    }
                }
            }
        }
        // srh rows 4b..4b+3, storage cols 4g+2..4g+5
        #pragma unroll
        for (int k = 0; k < 4; ++k)
            #pragma unroll
            for (int c = 0; c < 4; ++c)
                srh[4 * b + k][scw + 2 + c] = fast_sigmoid(racc[k][c]) * hold[k][c];
    }
    __syncthreads();

    // ---- interior: 4x4 blocking, 128 threads (8 row bands x 16 col groups) ----
    if (tid < 128) {
        const int rb = tid >> 4;            // 0..7 -> output rows oy..oy+3
        const int cg = tid & 15;            // 0..15 -> output cols ox..ox+3
        const int oy = 4 * rb;
        const int ox = 4 * cg;
        const float bu = b_update[0];

        float uacc[4][4], cacc[4][4], hold[4][4];
        #pragma unroll
        for (int k = 0; k < 4; ++k)
            #pragma unroll
            for (int c = 0; c < 4; ++c) { uacc[k][c] = bu; cacc[k][c] = 0.f; }

        #pragma unroll
        for (int ir = 0; ir < 8; ++ir) {
            const int sr = oy + 2 + ir;             // sx/sh storage row (spatial oy-2+ir)
            const float4 xa = *(const float4*)&sx[sr][ox + 4];
            const float4 xb = *(const float4*)&sx[sr][ox + 8];
            const float4 ha = *(const float4*)&sh[sr][ox + 4];
            const float4 hb = *(const float4*)&sh[sr][ox + 8];
            const float4 ra = *(const float4*)&srh[oy + ir][ox + 4];
            const float4 rb4 = *(const float4*)&srh[oy + ir][ox + 8];
            const float vx[8] = {xa.x, xa.y, xa.z, xa.w, xb.x, xb.y, xb.z, xb.w};
            const float vh[8] = {ha.x, ha.y, ha.z, ha.w, hb.x, hb.y, hb.z, hb.w};
            const float vr[8] = {ra.x, ra.y, ra.z, ra.w, rb4.x, rb4.y, rb4.z, rb4.w};
            if (ir >= 2 && ir <= 5) {
                #pragma unroll
                for (int c = 0; c < 4; ++c) hold[ir - 2][c] = vh[c + 2];
            }
            #pragma unroll
            for (int k = 0; k < 4; ++k) {
                const int dy = ir - k;
                if (dy >= 0 && dy <= 4) {
                    #pragma unroll
                    for (int dx = 0; dx < 5; ++dx) {
                        const float wux = w_update[dy * 5 + dx];
                        const float wuh = w_update[25 + dy * 5 + dx];
                        const float wox = w_out[dy * 5 + dx];
                        const float wor = w_out[25 + dy * 5 + dx];
                        #pragma unroll
                        for (int c = 0; c < 4; ++c) {
                            uacc[k][c] = fmaf(vx[c + dx], wux, uacc[k][c]);
                            uacc[k][c] = fmaf(vh[c + dx], wuh, uacc[k][c]);
                            cacc[k][c] = fmaf(vx[c + dx], wox, cacc[k][c]);
                            cacc[k][c] = fmaf(vr[c + dx], wor, cacc[k][c]);
                        }
                    }
                }
            }
        }

        const float* __restrict__ aw   = add_w  + (size_t)p * HW;
        float* __restrict__ hout = h_next + (size_t)p * HW;
        float* __restrict__ xso  = xs_t   + (size_t)p * HW;
        #pragma unroll
        for (int k = 0; k < 4; ++k) {
            const int gidx = (by + oy + k) * W + (bx + ox);
            const float4 aw4 = *(const float4*)&aw[gidx];
            const float awv[4] = {aw4.x, aw4.y, aw4.z, aw4.w};
            float hn[4], xv[4];
            #pragma unroll
            for (int c = 0; c < 4; ++c) {
                const float u = fast_sigmoid(uacc[k][c]);
                hn[c] = hold[k][c] + (cacc[k][c] - hold[k][c]) * u;
                xv[c] = fast_tanh(hn[c]) * awv[c];
            }
            *(float4*)&hout[gidx] = make_float4(hn[0], hn[1], hn[2], hn[3]);
            *(float4*)&xso[gidx]  = make_float4(xv[0], xv[1], xv[2], xv[3]);
        }
    }
}

// out_y[t,y,x] = bias[y,x] + sum_p xs[t,p,y,x], float4 per thread
__global__ __launch_bounds__(256) void reduce_out(
    const float* __restrict__ xs, const float* __restrict__ bias,
    float* __restrict__ out_y)
{
    const int i4  = blockIdx.x * 256 + threadIdx.x;      // < T*HW/4 = 294912
    const int t   = i4 / (HW / 4);
    const int yx4 = i4 - t * (HW / 4);
    const float4* __restrict__ src = (const float4*)(xs + (size_t)t * PHW) + yx4;
    const float4  b4 = ((const float4*)bias)[yx4];
    float a0[4] = {b4.x, b4.y, b4.z, b4.w};
    float a1[4] = {0.f, 0.f, 0.f, 0.f};
    #pragma unroll 8
    for (int p = 0; p < P; p += 2) {
        const float4 v0 = src[(size_t)p * (HW / 4)];
        const float4 v1 = src[(size_t)(p + 1) * (HW / 4)];
        a0[0] += v0.x; a0[1] += v0.y; a0[2] += v0.z; a0[3] += v0.w;
        a1[0] += v1.x; a1[1] += v1.y; a1[2] += v1.z; a1[3] += v1.w;
    }
    ((float4*)out_y)[i4] = make_float4(a0[0] + a1[0], a0[1] + a1[1],
                                       a0[2] + a1[2], a0[3] + a1[3]);
}

extern "C" void kernel_launch(void* const* d_in, const int* in_sizes, int n_in,
                              void* d_out, int out_size, void* d_ws, size_t ws_size,
                              hipStream_t stream) {
    const float* inputs   = (const float*)d_in[0];
    const float* w_reset  = (const float*)d_in[1];
    const float* b_reset  = (const float*)d_in[2];
    const float* w_update = (const float*)d_in[3];
    const float* b_update = (const float*)d_in[4];
    const float* w_out    = (const float*)d_in[5];
    const float* gam      = (const float*)d_in[6];
    const float* add_w    = (const float*)d_in[7];
    const float* bias     = (const float*)d_in[8];

    float* out_y = (float*)d_out;                 // T*H*W
    float* xs    = out_y + (size_t)T * HW;        // T*P*H*W

    float* h0 = (float*)d_ws;
    float* h1 = h0 + (size_t)PHW;

    hipMemsetAsync(h0, 0, (size_t)PHW * sizeof(float), stream);

    dim3 grid(W / TILE_W, H / TILE_H, P);         // (4, 4, 64) = 1024 blocks
    for (int t = 0; t < T; ++t) {
        const float* hp = (t & 1) ? h1 : h0;
        float*       hn = (t & 1) ? h0 : h1;
        gru_step<<<grid, 256, 0, stream>>>(
            inputs + (size_t)t * PHW, gam, hp, hn,
            w_update, b_update, w_reset, b_reset, w_out,
            add_w, xs + (size_t)t * PHW);
    }

    const int nout4 = T * HW / 4;                 // 294912
    reduce_out<<<nout4 / 256, 256, 0, stream>>>(xs, bias, out_y);
}

// Round 4
// 778.430 us; speedup vs baseline: 1.4570x; 1.1375x over previous
//
#include <hip/hip_runtime.h>

constexpr int T = 36, P = 64, H = 128, W = 256;
constexpr int HW  = H * W;        // 32768
constexpr int PHW = P * HW;       // 2097152

constexpr int TILE_H = 32, TILE_W = 64;
// sx/sh: storage row = spatial + 4 (spatial -4..35), storage col = spatial + 6
// (staged spatial cols -4..67 -> storage 2..73; cols 0,1,74,75 zero pads).
constexpr int SXH = 40, SW = 76;
// srh: storage row = spatial + 2 (spatial -2..33), storage col = spatial + 6.
constexpr int SRH = 36, SRW = 76;

__device__ __forceinline__ float fast_sigmoid(float z) {
    float e = __expf(-z);
    return __builtin_amdgcn_rcpf(1.0f + e);
}
__device__ __forceinline__ float fast_tanh(float x) {
    float e = __expf(-2.0f * fabsf(x));
    float t = (1.0f - e) * __builtin_amdgcn_rcpf(1.0f + e);
    return copysignf(t, x);
}

__global__ __launch_bounds__(256, 4) void gru_step(
    const float* __restrict__ x_t,
    const float* __restrict__ gam,
    const float* __restrict__ h_prev,
    float* __restrict__ h_next,
    const float* __restrict__ w_update, const float* __restrict__ b_update,
    const float* __restrict__ w_reset,  const float* __restrict__ b_reset,
    const float* __restrict__ w_out,
    const float* __restrict__ add_w,
    float* __restrict__ xs_t,
    int is_t0)
{
    __shared__ __align__(16) float sx[SXH][SW];
    __shared__ __align__(16) float sh[SXH][SW];
    __shared__ __align__(16) float srh[SRH][SRW];

    const int tid = threadIdx.x;
    const int p   = blockIdx.z;
    const int by  = blockIdx.y * TILE_H;
    const int bx  = blockIdx.x * TILE_W;

    const float gamma = gam[p];
    const float* __restrict__ xin = x_t    + (size_t)p * HW;
    const float* __restrict__ hin = h_prev + (size_t)p * HW;

    // ---- stage: float4 loads, spatial cols -4..67 (18 float4/row), rows -4..35 ----
    for (int s = tid; s < SXH * 18; s += 256) {
        const int r  = s / 18;              // storage row
        const int c4 = s - r * 18;          // float4 index
        const int gy = by + r - 4;
        const int gx = bx + 4 * c4 - 4;     // multiple of 4; all-in or all-out
        float4 xv = make_float4(0.f, 0.f, 0.f, 0.f);
        float4 hv = xv;
        if ((unsigned)gy < (unsigned)H && (unsigned)gx < (unsigned)W) {
            const int idx = gy * W + gx;
            xv = *(const float4*)&xin[idx];
            if (!is_t0) hv = *(const float4*)&hin[idx];
            xv.x *= gamma; xv.y *= gamma; xv.z *= gamma; xv.w *= gamma;
        }
        const int sc = 2 + 4 * c4;          // storage col (== spatial+6)
        sx[r][sc] = xv.x; sx[r][sc+1] = xv.y; sx[r][sc+2] = xv.z; sx[r][sc+3] = xv.w;
        sh[r][sc] = hv.x; sh[r][sc+1] = hv.y; sh[r][sc+2] = hv.z; sh[r][sc+3] = hv.w;
    }
    // zero pad columns {0,1,74,75}
    if (tid < 160) {
        const int r = tid >> 2;
        const int c = tid & 3;
        const int col = (c < 2) ? c : 72 + c;   // 0,1,74,75
        sx[r][col] = 0.f;
        sh[r][col] = 0.f;
    }
    __syncthreads();

    // ---- reset: 3x4 blocking, 12 row-bands x 18 col-groups = 216 slots ----
    if (tid < 216) {
        const int b = tid / 18;             // 0..11 -> output spatial rows 3b-2..3b
        const int g = tid - b * 18;         // 0..17 -> output spatial cols 4g-4..4g-1
        const int sr0 = 3 * b;              // window storage rows sr0..sr0+6
        const int scw = 4 * g;              // window storage cols scw..scw+7 (16B aligned)
        const float br = b_reset[0];
        float racc[3][4], hold[3][4];
        #pragma unroll
        for (int k = 0; k < 3; ++k)
            #pragma unroll
            for (int c = 0; c < 4; ++c) racc[k][c] = br;

        #pragma unroll
        for (int ir = 0; ir < 7; ++ir) {
            const float4 xa = *(const float4*)&sx[sr0 + ir][scw];
            const float4 xb = *(const float4*)&sx[sr0 + ir][scw + 4];
            const float4 ha = *(const float4*)&sh[sr0 + ir][scw];
            const float4 hb = *(const float4*)&sh[sr0 + ir][scw + 4];
            const float vx[8] = {xa.x, xa.y, xa.z, xa.w, xb.x, xb.y, xb.z, xb.w};
            const float vh[8] = {ha.x, ha.y, ha.z, ha.w, hb.x, hb.y, hb.z, hb.w};
            if (ir >= 2 && ir <= 4) {       // h at output rows k = ir-2
                #pragma unroll
                for (int c = 0; c < 4; ++c) hold[ir - 2][c] = vh[c + 2];
            }
            #pragma unroll
            for (int k = 0; k < 3; ++k) {
                const int dy = ir - k;
                if (dy >= 0 && dy <= 4) {
                    #pragma unroll
                    for (int dx = 0; dx < 5; ++dx) {
                        const float wx = w_reset[dy * 5 + dx];
                        const float wh = w_reset[25 + dy * 5 + dx];
                        #pragma unroll
                        for (int c = 0; c < 4; ++c) {
                            racc[k][c] = fmaf(vx[c + dx], wx, racc[k][c]);
                            racc[k][c] = fmaf(vh[c + dx], wh, racc[k][c]);
                        }
                    }
                }
            }
        }
        // srh storage rows 3b..3b+2, storage cols 4g+2..4g+5
        #pragma unroll
        for (int k = 0; k < 3; ++k)
            #pragma unroll
            for (int c = 0; c < 4; ++c)
                srh[sr0 + k][scw + 2 + c] = fast_sigmoid(racc[k][c]) * hold[k][c];
    }
    __syncthreads();

    // ---- interior: 2x4 blocking, 256 slots (16 row-bands x 16 col-groups) ----
    {
        const int rb = tid >> 4;            // 0..15 -> output rows oy, oy+1
        const int cg = tid & 15;            // 0..15 -> output cols ox..ox+3
        const int oy = 2 * rb;
        const int ox = 4 * cg;
        const float bu = b_update[0];

        // prefetch epilogue operands early (hides global latency under FMAs)
        const float* __restrict__ aw = add_w + (size_t)p * HW;
        const int gidx0 = (by + oy) * W + (bx + ox);
        const float4 aw0 = *(const float4*)&aw[gidx0];
        const float4 aw1 = *(const float4*)&aw[gidx0 + W];

        float uacc[2][4], cacc[2][4], hold[2][4];
        #pragma unroll
        for (int k = 0; k < 2; ++k)
            #pragma unroll
            for (int c = 0; c < 4; ++c) { uacc[k][c] = bu; cacc[k][c] = 0.f; }

        #pragma unroll
        for (int ir = 0; ir < 6; ++ir) {
            const int sr = oy + 2 + ir;             // sx/sh storage row (spatial oy-2+ir)
            const float4 xa = *(const float4*)&sx[sr][ox + 4];
            const float4 xb = *(const float4*)&sx[sr][ox + 8];
            const float4 ha = *(const float4*)&sh[sr][ox + 4];
            const float4 hb = *(const float4*)&sh[sr][ox + 8];
            const float4 ra = *(const float4*)&srh[oy + ir][ox + 4];
            const float4 rb4 = *(const float4*)&srh[oy + ir][ox + 8];
            const float vx[8] = {xa.x, xa.y, xa.z, xa.w, xb.x, xb.y, xb.z, xb.w};
            const float vh[8] = {ha.x, ha.y, ha.z, ha.w, hb.x, hb.y, hb.z, hb.w};
            const float vr[8] = {ra.x, ra.y, ra.z, ra.w, rb4.x, rb4.y, rb4.z, rb4.w};
            if (ir == 2) {
                #pragma unroll
                for (int c = 0; c < 4; ++c) hold[0][c] = vh[c + 2];
            }
            if (ir == 3) {
                #pragma unroll
                for (int c = 0; c < 4; ++c) hold[1][c] = vh[c + 2];
            }
            #pragma unroll
            for (int k = 0; k < 2; ++k) {
                const int dy = ir - k;
                if (dy >= 0 && dy <= 4) {
                    #pragma unroll
                    for (int dx = 0; dx < 5; ++dx) {
                        const float wux = w_update[dy * 5 + dx];
                        const float wuh = w_update[25 + dy * 5 + dx];
                        const float wox = w_out[dy * 5 + dx];
                        const float wor = w_out[25 + dy * 5 + dx];
                        #pragma unroll
                        for (int c = 0; c < 4; ++c) {
                            uacc[k][c] = fmaf(vx[c + dx], wux, uacc[k][c]);
                            uacc[k][c] = fmaf(vh[c + dx], wuh, uacc[k][c]);
                            cacc[k][c] = fmaf(vx[c + dx], wox, cacc[k][c]);
                            cacc[k][c] = fmaf(vr[c + dx], wor, cacc[k][c]);
                        }
                    }
                }
            }
        }

        float* __restrict__ hout = h_next + (size_t)p * HW;
        float* __restrict__ xso  = xs_t   + (size_t)p * HW;
        const float awv[2][4] = {{aw0.x, aw0.y, aw0.z, aw0.w},
                                 {aw1.x, aw1.y, aw1.z, aw1.w}};
        #pragma unroll
        for (int k = 0; k < 2; ++k) {
            const int gidx = gidx0 + k * W;
            float hn[4], xv[4];
            #pragma unroll
            for (int c = 0; c < 4; ++c) {
                const float u = fast_sigmoid(uacc[k][c]);
                hn[c] = hold[k][c] + (cacc[k][c] - hold[k][c]) * u;
                xv[c] = fast_tanh(hn[c]) * awv[k][c];
            }
            *(float4*)&hout[gidx] = make_float4(hn[0], hn[1], hn[2], hn[3]);
            *(float4*)&xso[gidx]  = make_float4(xv[0], xv[1], xv[2], xv[3]);
        }
    }
}

// out_y[t,y,x] = bias[y,x] + sum_p xs[t,p,y,x], float4 per thread
__global__ __launch_bounds__(256) void reduce_out(
    const float* __restrict__ xs, const float* __restrict__ bias,
    float* __restrict__ out_y)
{
    const int i4  = blockIdx.x * 256 + threadIdx.x;      // < T*HW/4 = 294912
    const int t   = i4 / (HW / 4);
    const int yx4 = i4 - t * (HW / 4);
    const float4* __restrict__ src = (const float4*)(xs + (size_t)t * PHW) + yx4;
    const float4  b4 = ((const float4*)bias)[yx4];
    float a0[4] = {b4.x, b4.y, b4.z, b4.w};
    float a1[4] = {0.f, 0.f, 0.f, 0.f};
    #pragma unroll 8
    for (int p = 0; p < P; p += 2) {
        const float4 v0 = src[(size_t)p * (HW / 4)];
        const float4 v1 = src[(size_t)(p + 1) * (HW / 4)];
        a0[0] += v0.x; a0[1] += v0.y; a0[2] += v0.z; a0[3] += v0.w;
        a1[0] += v1.x; a1[1] += v1.y; a1[2] += v1.z; a1[3] += v1.w;
    }
    ((float4*)out_y)[i4] = make_float4(a0[0] + a1[0], a0[1] + a1[1],
                                       a0[2] + a1[2], a0[3] + a1[3]);
}

extern "C" void kernel_launch(void* const* d_in, const int* in_sizes, int n_in,
                              void* d_out, int out_size, void* d_ws, size_t ws_size,
                              hipStream_t stream) {
    const float* inputs   = (const float*)d_in[0];
    const float* w_reset  = (const float*)d_in[1];
    const float* b_reset  = (const float*)d_in[2];
    const float* w_update = (const float*)d_in[3];
    const float* b_update = (const float*)d_in[4];
    const float* w_out    = (const float*)d_in[5];
    const float* gam      = (const float*)d_in[6];
    const float* add_w    = (const float*)d_in[7];
    const float* bias     = (const float*)d_in[8];

    float* out_y = (float*)d_out;                 // T*H*W
    float* xs    = out_y + (size_t)T * HW;        // T*P*H*W

    float* h0 = (float*)d_ws;
    float* h1 = h0 + (size_t)PHW;

    dim3 grid(W / TILE_W, H / TILE_H, P);         // (4, 4, 64) = 1024 blocks
    for (int t = 0; t < T; ++t) {
        const float* hp = (t & 1) ? h1 : h0;      // t=0: h0 is never read (is_t0)
        float*       hn = (t & 1) ? h0 : h1;
        gru_step<<<grid, 256, 0, stream>>>(
            inputs + (size_t)t * PHW, gam, hp, hn,
            w_update, b_update, w_reset, b_reset, w_out,
            add_w, xs + (size_t)t * PHW, (t == 0) ? 1 : 0);
    }

    const int nout4 = T * HW / 4;                 // 294912
    reduce_out<<<nout4 / 256, 256, 0, stream>>>(xs, bias, out_y);
}